// Round 3
// baseline (763.646 us; speedup 1.0000x reference)
//
#include <hip/hip_runtime.h>

#define IN_DIM     128
#define OUT_DIM    64
#define BSHIFT     6                  // 64 nodes per bucket
#define BSZ        64
#define NBUCK_MAX  2048               // covers N <= 131072
#define EPB        4096               // edges per block in hist/bucket passes

// ---------------------------------------------------------------------------
// Zero ints (grid-stride)
// ---------------------------------------------------------------------------
__global__ void zero_i_kernel(int* __restrict__ p, int n) {
    int i = blockIdx.x * blockDim.x + threadIdx.x;
    int s = gridDim.x * blockDim.x;
    for (; i < n; i += s) p[i] = 0;
}

// ---------------------------------------------------------------------------
// Pass A: per-node degree (global atomics) + block-aggregated bucket histogram
// ---------------------------------------------------------------------------
__global__ __launch_bounds__(256) void hist_kernel(
        const int* __restrict__ col, int* __restrict__ deg,
        int* __restrict__ bhist, int E, int nbuck) {
    __shared__ int h[NBUCK_MAX];
    for (int i = threadIdx.x; i < nbuck; i += 256) h[i] = 0;
    __syncthreads();

    const int base = blockIdx.x * EPB;
    const int end  = min(base + EPB, E);
    for (int e = base + threadIdx.x; e < end; e += 256) {
        int c = col[e];
        atomicAdd(&deg[c], 1);
        atomicAdd(&h[c >> BSHIFT], 1);
    }
    __syncthreads();
    for (int i = threadIdx.x; i < nbuck; i += 256) {
        int v = h[i];
        if (v) atomicAdd(&bhist[i], v);
    }
}

// ---------------------------------------------------------------------------
// dis[i] = deg>0 ? rsqrt(deg) : 0
// ---------------------------------------------------------------------------
__global__ void dis_kernel(const int* __restrict__ deg, float* __restrict__ dis, int n) {
    int i = blockIdx.x * blockDim.x + threadIdx.x;
    int s = gridDim.x * blockDim.x;
    for (; i < n; i += s) {
        float d = (float)deg[i];
        dis[i] = (d > 0.f) ? rsqrtf(d) : 0.f;
    }
}

// ---------------------------------------------------------------------------
// hs = (x @ W) * dis[row]
// ---------------------------------------------------------------------------
__global__ __launch_bounds__(256) void linear_kernel(
        const float* __restrict__ x, const float* __restrict__ W,
        const float* __restrict__ dis, float* __restrict__ hs, int nrows) {
    __shared__ float sW[IN_DIM * OUT_DIM];   // 32 KB
    __shared__ float sx[4][IN_DIM];

    const int tid = threadIdx.x;
    for (int i = tid; i < IN_DIM * OUT_DIM; i += 256) sW[i] = W[i];
    __syncthreads();

    const int wave = tid >> 6;
    const int lane = tid & 63;

    for (int r = blockIdx.x * 4 + wave; r < nrows; r += gridDim.x * 4) {
        sx[wave][lane]      = x[(size_t)r * IN_DIM + lane];
        sx[wave][lane + 64] = x[(size_t)r * IN_DIM + 64 + lane];

        float acc = 0.f;
#pragma unroll
        for (int k = 0; k < IN_DIM; k += 4) {
            float4 xv = *reinterpret_cast<const float4*>(&sx[wave][k]);
            acc = fmaf(xv.x, sW[(k + 0) * OUT_DIM + lane], acc);
            acc = fmaf(xv.y, sW[(k + 1) * OUT_DIM + lane], acc);
            acc = fmaf(xv.z, sW[(k + 2) * OUT_DIM + lane], acc);
            acc = fmaf(xv.w, sW[(k + 3) * OUT_DIM + lane], acc);
        }
        hs[(size_t)r * OUT_DIM + lane] = acc * dis[r];
    }
}

// ---------------------------------------------------------------------------
// Exclusive scan of bhist -> bstart (single block, 8 elems/thread)
// ---------------------------------------------------------------------------
__global__ __launch_bounds__(256) void scanb_kernel(
        const int* __restrict__ bhist, int* __restrict__ bstart, int nbuck) {
    __shared__ int ssum[256];
    const int t = threadIdx.x;
    int v[8];
    int run = 0;
#pragma unroll
    for (int j = 0; j < 8; ++j) {
        int idx = t * 8 + j;
        int x = (idx < nbuck) ? bhist[idx] : 0;
        v[j] = run;            // exclusive within thread
        run += x;
    }
    ssum[t] = run;
    __syncthreads();
    for (int off = 1; off < 256; off <<= 1) {
        int tmp = (t >= off) ? ssum[t - off] : 0;
        __syncthreads();
        ssum[t] += tmp;
        __syncthreads();
    }
    int offset = (t > 0) ? ssum[t - 1] : 0;
#pragma unroll
    for (int j = 0; j < 8; ++j) {
        int idx = t * 8 + j;
        if (idx < nbuck) bstart[idx] = offset + v[j];
    }
}

// ---------------------------------------------------------------------------
// Pass B: scatter edges into bucket-major tmp, packed (r<<6 | c&63).
// Block-aggregated reserve -> per-bucket sequential write streams.
// ---------------------------------------------------------------------------
__global__ __launch_bounds__(256) void bucket_kernel(
        const int* __restrict__ eidx, const int* __restrict__ bstart,
        int* __restrict__ bcursor, int* __restrict__ tmp, int E, int nbuck) {
    __shared__ int hcnt[NBUCK_MAX];
    __shared__ int hbase[NBUCK_MAX];
    for (int i = threadIdx.x; i < nbuck; i += 256) hcnt[i] = 0;
    __syncthreads();

    const int base = blockIdx.x * EPB;
    const int end  = min(base + EPB, E);

    for (int e = base + threadIdx.x; e < end; e += 256) {
        int c = eidx[E + e];
        atomicAdd(&hcnt[c >> BSHIFT], 1);
    }
    __syncthreads();
    for (int i = threadIdx.x; i < nbuck; i += 256) {
        int n = hcnt[i];
        hbase[i] = n ? atomicAdd(&bcursor[i], n) : 0;
        hcnt[i] = 0;           // reuse as local cursor
    }
    __syncthreads();
    for (int e = base + threadIdx.x; e < end; e += 256) {
        int r = eidx[e];
        int c = eidx[E + e];
        int bb = c >> BSHIFT;
        int ofs = atomicAdd(&hcnt[bb], 1);
        tmp[bstart[bb] + hbase[bb] + ofs] = (r << BSHIFT) | (c & (BSZ - 1));
    }
}

// ---------------------------------------------------------------------------
// Merged aggregate + bias + PReLU: one block per bucket, 64x64 f32 LDS tile.
// Per edge: wave gathers hs[r][lane] (256B coalesced), ds_add into acc row.
// ---------------------------------------------------------------------------
__global__ __launch_bounds__(256) void agg_kernel(
        const int* __restrict__ tmp, const int* __restrict__ bstart,
        const int* __restrict__ bhist, const float* __restrict__ hs,
        const float* __restrict__ dis, const float* __restrict__ bias,
        const float* __restrict__ prelu_a, float* __restrict__ out, int N) {
    __shared__ float acc[BSZ * OUT_DIM];       // 16 KB

    for (int i = threadIdx.x; i < BSZ * OUT_DIM; i += 256) acc[i] = 0.f;
    __syncthreads();

    const int bucket = blockIdx.x;
    const int beg = bstart[bucket];
    const int cnt = bhist[bucket];
    const int wave = threadIdx.x >> 6;
    const int lane = threadIdx.x & 63;

    int i = wave;
    // 4-deep unroll per wave: 4 independent gathers in flight
    for (; i + 12 < cnt; i += 16) {
        int p0 = tmp[beg + i];
        int p1 = tmp[beg + i + 4];
        int p2 = tmp[beg + i + 8];
        int p3 = tmp[beg + i + 12];
        float v0 = hs[(size_t)(p0 >> BSHIFT) * OUT_DIM + lane];
        float v1 = hs[(size_t)(p1 >> BSHIFT) * OUT_DIM + lane];
        float v2 = hs[(size_t)(p2 >> BSHIFT) * OUT_DIM + lane];
        float v3 = hs[(size_t)(p3 >> BSHIFT) * OUT_DIM + lane];
        atomicAdd(&acc[(p0 & (BSZ - 1)) * OUT_DIM + lane], v0);
        atomicAdd(&acc[(p1 & (BSZ - 1)) * OUT_DIM + lane], v1);
        atomicAdd(&acc[(p2 & (BSZ - 1)) * OUT_DIM + lane], v2);
        atomicAdd(&acc[(p3 & (BSZ - 1)) * OUT_DIM + lane], v3);
    }
    for (; i < cnt; i += 4) {
        int p = tmp[beg + i];
        float v = hs[(size_t)(p >> BSHIFT) * OUT_DIM + lane];
        atomicAdd(&acc[(p & (BSZ - 1)) * OUT_DIM + lane], v);
    }
    __syncthreads();

    const float a  = prelu_a[0];
    const float bl = bias[lane];
    const int nodebase = bucket << BSHIFT;
    for (int j = wave; j < BSZ; j += 4) {
        int node = nodebase + j;
        if (node < N) {
            float o = acc[j * OUT_DIM + lane] * dis[node] + bl;
            out[(size_t)node * OUT_DIM + lane] = (o >= 0.f) ? o : a * o;
        }
    }
}

extern "C" void kernel_launch(void* const* d_in, const int* in_sizes, int n_in,
                              void* d_out, int out_size, void* d_ws, size_t ws_size,
                              hipStream_t stream) {
    const float* x    = (const float*)d_in[0];
    const int*   eidx = (const int*)d_in[1];
    const float* W    = (const float*)d_in[2];
    const float* b    = (const float*)d_in[3];
    const float* pa   = (const float*)d_in[4];
    float* out = (float*)d_out;

    const int N = in_sizes[0] / IN_DIM;        // 100000
    const int E = in_sizes[1] / 2;             // 1600000
    const int nbuck = (N + BSZ - 1) >> BSHIFT; // 1563 (<= NBUCK_MAX)
    const int nchunk = (E + EPB - 1) / EPB;    // 391

    // workspace layout (4-byte elements):
    float* hs      = (float*)d_ws;                       // N*64
    int*   deg     = (int*)(hs + (size_t)N * OUT_DIM);   // N
    int*   bhist   = deg + N;                            // NBUCK_MAX
    int*   bcursor = bhist + NBUCK_MAX;                  // NBUCK_MAX
    int*   bstart  = bcursor + NBUCK_MAX;                // NBUCK_MAX
    float* dis     = (float*)(bstart + NBUCK_MAX);       // N
    int*   tmp     = (int*)(dis + N);                    // E

    // 1) zero deg + bhist + bcursor (contiguous)
    zero_i_kernel<<<512, 256, 0, stream>>>(deg, N + 2 * NBUCK_MAX);

    // 2) degree + bucket histogram
    hist_kernel<<<nchunk, 256, 0, stream>>>(eidx + E, deg, bhist, E, nbuck);

    // 3) dis = deg^{-1/2}
    dis_kernel<<<(N + 255) / 256, 256, 0, stream>>>(deg, dis, N);

    // 4) hs = (x @ W) * dis[row]
    linear_kernel<<<2048, 256, 0, stream>>>(x, W, dis, hs, N);

    // 5) scan bhist -> bstart
    scanb_kernel<<<1, 256, 0, stream>>>(bhist, bstart, nbuck);

    // 6) bucket scatter
    bucket_kernel<<<nchunk, 256, 0, stream>>>(eidx, bstart, bcursor, tmp, E, nbuck);

    // 7) merged aggregate + bias + PReLU
    agg_kernel<<<nbuck, 256, 0, stream>>>(tmp, bstart, bhist, hs, dis, b, pa, out, N);
}

// Round 4
// 265.474 us; speedup vs baseline: 2.8765x; 2.8765x over previous
//
#include <hip/hip_runtime.h>

#define IN_DIM     128
#define OUT_DIM    64
#define BSHIFT     6                  // 64 nodes per bucket
#define BSZ        64
#define NBUCK_MAX  2048               // covers N <= 131072
#define EPB        8192               // edges per block in bucket pass

// ---------------------------------------------------------------------------
// Zero ints (grid-stride)
// ---------------------------------------------------------------------------
__global__ void zero_i_kernel(int* __restrict__ p, int n) {
    int i = blockIdx.x * blockDim.x + threadIdx.x;
    int s = gridDim.x * blockDim.x;
    for (; i < n; i += s) p[i] = 0;
}

// ---------------------------------------------------------------------------
// deg[col[e]] += 1  (int)
// ---------------------------------------------------------------------------
__global__ void degi_kernel(const int* __restrict__ col, int* __restrict__ deg, int E) {
    int i = blockIdx.x * blockDim.x + threadIdx.x;
    int s = gridDim.x * blockDim.x;
    for (; i < E; i += s) atomicAdd(&deg[col[i]], 1);
}

// ---------------------------------------------------------------------------
// dis[i] = deg>0 ? rsqrt(deg) : 0
// ---------------------------------------------------------------------------
__global__ void dis_kernel(const int* __restrict__ deg, float* __restrict__ dis, int n) {
    int i = blockIdx.x * blockDim.x + threadIdx.x;
    int s = gridDim.x * blockDim.x;
    for (; i < n; i += s) {
        float d = (float)deg[i];
        dis[i] = (d > 0.f) ? rsqrtf(d) : 0.f;
    }
}

// ---------------------------------------------------------------------------
// hs = (x @ W) * dis[row]
// ---------------------------------------------------------------------------
__global__ __launch_bounds__(256) void linear_kernel(
        const float* __restrict__ x, const float* __restrict__ W,
        const float* __restrict__ dis, float* __restrict__ hs, int nrows) {
    __shared__ float sW[IN_DIM * OUT_DIM];   // 32 KB
    __shared__ float sx[4][IN_DIM];

    const int tid = threadIdx.x;
    for (int i = tid; i < IN_DIM * OUT_DIM; i += 256) sW[i] = W[i];
    __syncthreads();

    const int wave = tid >> 6;
    const int lane = tid & 63;

    for (int r = blockIdx.x * 4 + wave; r < nrows; r += gridDim.x * 4) {
        sx[wave][lane]      = x[(size_t)r * IN_DIM + lane];
        sx[wave][lane + 64] = x[(size_t)r * IN_DIM + 64 + lane];

        float acc = 0.f;
#pragma unroll
        for (int k = 0; k < IN_DIM; k += 4) {
            float4 xv = *reinterpret_cast<const float4*>(&sx[wave][k]);
            acc = fmaf(xv.x, sW[(k + 0) * OUT_DIM + lane], acc);
            acc = fmaf(xv.y, sW[(k + 1) * OUT_DIM + lane], acc);
            acc = fmaf(xv.z, sW[(k + 2) * OUT_DIM + lane], acc);
            acc = fmaf(xv.w, sW[(k + 3) * OUT_DIM + lane], acc);
        }
        hs[(size_t)r * OUT_DIM + lane] = acc * dis[r];
    }
}

// ---------------------------------------------------------------------------
// Prefix scan of deg -> rowptr (exclusive), 3-kernel hierarchical
// ---------------------------------------------------------------------------
__global__ void scan1_kernel(const int* __restrict__ deg, int* __restrict__ rowptr,
                             int* __restrict__ bsums, int n) {
    __shared__ int s[256];
    const int t = threadIdx.x;
    const int i = blockIdx.x * 256 + t;
    int v = (i < n) ? deg[i] : 0;
    s[t] = v;
    __syncthreads();
    for (int off = 1; off < 256; off <<= 1) {
        int tmp = (t >= off) ? s[t - off] : 0;
        __syncthreads();
        s[t] += tmp;
        __syncthreads();
    }
    if (i < n) rowptr[i] = s[t] - v;
    if (t == 255) bsums[blockIdx.x] = s[255];
}

__global__ void scan2_kernel(const int* __restrict__ bsums, int* __restrict__ boffs, int nb) {
    if (threadIdx.x == 0 && blockIdx.x == 0) {
        int run = 0;
        for (int i = 0; i < nb; ++i) { int v = bsums[i]; boffs[i] = run; run += v; }
    }
}

__global__ void scan3_kernel(int* __restrict__ rowptr, const int* __restrict__ boffs, int n) {
    int i = blockIdx.x * blockDim.x + threadIdx.x;
    int s = gridDim.x * blockDim.x;
    for (; i < n; i += s) rowptr[i] += boffs[i >> 8];
}

// ---------------------------------------------------------------------------
// Phase 1: scatter edges into bucket-major tmp, packed (r<<6 | c&63).
// Block-aggregated reserve -> per-bucket ~sequential write runs.
// bstart[b] == rowptr[b<<6] because buckets are node-aligned.
// ---------------------------------------------------------------------------
__global__ __launch_bounds__(256) void bucket_kernel(
        const int* __restrict__ eidx, const int* __restrict__ rowptr,
        int* __restrict__ bcursor, int* __restrict__ tmp, int E, int nbuck) {
    __shared__ int hcnt[NBUCK_MAX];
    __shared__ int hbase[NBUCK_MAX];
    for (int i = threadIdx.x; i < nbuck; i += 256) hcnt[i] = 0;
    __syncthreads();

    const int base = blockIdx.x * EPB;
    const int end  = min(base + EPB, E);

    for (int e = base + threadIdx.x; e < end; e += 256) {
        atomicAdd(&hcnt[eidx[E + e] >> BSHIFT], 1);
    }
    __syncthreads();
    for (int i = threadIdx.x; i < nbuck; i += 256) {
        int n = hcnt[i];
        // fold bucket base (rowptr of first node) into per-block base
        hbase[i] = n ? (rowptr[i << BSHIFT] + atomicAdd(&bcursor[i], n)) : 0;
        hcnt[i] = 0;           // reuse as local cursor
    }
    __syncthreads();
    for (int e = base + threadIdx.x; e < end; e += 256) {
        int r = eidx[e];
        int c = eidx[E + e];
        int bb = c >> BSHIFT;
        int ofs = atomicAdd(&hcnt[bb], 1);
        tmp[hbase[bb] + ofs] = (r << BSHIFT) | (c & (BSZ - 1));
    }
}

// ---------------------------------------------------------------------------
// Phase 2: per-bucket local counting placement into exact CSR position.
// Reads its contiguous tmp region coalesced; writes stay within the same
// ~4KB region (L2-absorbed).
// ---------------------------------------------------------------------------
__global__ __launch_bounds__(256) void sortloc_kernel(
        const int* __restrict__ tmp, const int* __restrict__ rowptr,
        int* __restrict__ src, int N, int E) {
    __shared__ int srow[BSZ];
    __shared__ int scur[BSZ];
    __shared__ int sbeg, send;

    const int nodebase = blockIdx.x << BSHIFT;
    if (threadIdx.x < BSZ) {
        int node = nodebase + threadIdx.x;
        srow[threadIdx.x] = (node < N) ? rowptr[node] : E;
        scur[threadIdx.x] = 0;
    }
    if (threadIdx.x == 0) {
        sbeg = rowptr[nodebase];
        int nb2 = nodebase + BSZ;
        send = (nb2 < N) ? rowptr[nb2] : E;
    }
    __syncthreads();

    for (int i = sbeg + threadIdx.x; i < send; i += 256) {
        int p = tmp[i];
        int c = p & (BSZ - 1);
        int pos = srow[c] + atomicAdd(&scur[c], 1);
        src[pos] = p >> BSHIFT;
    }
}

// ---------------------------------------------------------------------------
// Aggregate + bias + PReLU: one wave per target node, lane = column
// ---------------------------------------------------------------------------
__global__ __launch_bounds__(256) void agg_kernel(
        const int* __restrict__ rowptr, const int* __restrict__ src,
        const float* __restrict__ hs, const float* __restrict__ dis,
        const float* __restrict__ b, const float* __restrict__ prelu_a,
        float* __restrict__ out, int N, int E) {
    const int lane = threadIdx.x & 63;
    const int node = (blockIdx.x * blockDim.x + threadIdx.x) >> 6;
    if (node >= N) return;

    const int beg = rowptr[node];
    const int end = (node + 1 < N) ? rowptr[node + 1] : E;

    float acc = 0.f;
    int p = beg;
    for (; p + 4 <= end; p += 4) {
        int r0 = src[p], r1 = src[p + 1], r2 = src[p + 2], r3 = src[p + 3];
        float v0 = hs[(size_t)r0 * OUT_DIM + lane];
        float v1 = hs[(size_t)r1 * OUT_DIM + lane];
        float v2 = hs[(size_t)r2 * OUT_DIM + lane];
        float v3 = hs[(size_t)r3 * OUT_DIM + lane];
        acc += v0 + v1 + v2 + v3;
    }
    for (; p < end; ++p) acc += hs[(size_t)src[p] * OUT_DIM + lane];

    float o = acc * dis[node] + b[lane];
    out[(size_t)node * OUT_DIM + lane] = (o >= 0.f) ? o : prelu_a[0] * o;
}

extern "C" void kernel_launch(void* const* d_in, const int* in_sizes, int n_in,
                              void* d_out, int out_size, void* d_ws, size_t ws_size,
                              hipStream_t stream) {
    const float* x    = (const float*)d_in[0];
    const int*   eidx = (const int*)d_in[1];
    const float* W    = (const float*)d_in[2];
    const float* b    = (const float*)d_in[3];
    const float* pa   = (const float*)d_in[4];
    float* out = (float*)d_out;

    const int N = in_sizes[0] / IN_DIM;        // 100000
    const int E = in_sizes[1] / 2;             // 1600000
    const int nbuck = (N + BSZ - 1) >> BSHIFT; // 1563
    const int NB = (N + 255) / 256;            // scan blocks
    const int nchunk = (E + EPB - 1) / EPB;    // 196

    // workspace layout (4-byte elements):
    float* hs      = (float*)d_ws;                       // N*64
    int*   deg     = (int*)(hs + (size_t)N * OUT_DIM);   // N
    int*   bcursor = deg + N;                            // NBUCK_MAX
    int*   rowptr  = bcursor + NBUCK_MAX;                // N
    float* dis     = (float*)(rowptr + N);               // N
    int*   bsums   = (int*)(dis + N);                    // NB
    int*   boffs   = bsums + NB;                         // NB
    int*   tmp     = boffs + NB;                         // E
    int*   src     = tmp + E;                            // E

    // 1) zero deg + bcursor (contiguous)
    zero_i_kernel<<<512, 256, 0, stream>>>(deg, N + NBUCK_MAX);

    // 2) degree over targets
    degi_kernel<<<2048, 256, 0, stream>>>(eidx + E, deg, E);

    // 3) dis = deg^{-1/2}
    dis_kernel<<<(N + 255) / 256, 256, 0, stream>>>(deg, dis, N);

    // 4) hs = (x @ W) * dis[row]
    linear_kernel<<<2048, 256, 0, stream>>>(x, W, dis, hs, N);

    // 5) scan deg -> rowptr (exclusive)
    scan1_kernel<<<NB, 256, 0, stream>>>(deg, rowptr, bsums, N);
    scan2_kernel<<<1, 64, 0, stream>>>(bsums, boffs, NB);
    scan3_kernel<<<512, 256, 0, stream>>>(rowptr, boffs, N);

    // 6) bucket-major scatter (sequential-run writes)
    bucket_kernel<<<nchunk, 256, 0, stream>>>(eidx, rowptr, bcursor, tmp, E, nbuck);

    // 7) per-bucket exact CSR placement (L2-local writes)
    sortloc_kernel<<<nbuck, 256, 0, stream>>>(tmp, rowptr, src, N, E);

    // 8) aggregate + bias + PReLU
    agg_kernel<<<(N * 64 + 255) / 256, 256, 0, stream>>>(
        rowptr, src, hs, dis, b, pa, out, N, E);
}

// Round 5
// 185.912 us; speedup vs baseline: 4.1076x; 1.4280x over previous
//
#include <hip/hip_runtime.h>

#define IN_DIM     128
#define OUT_DIM    64
#define BSHIFT     6                  // 64 nodes per bucket
#define BSZ        64
#define NBUCK_MAX  2048               // covers N <= 131072
#define EPB        4096               // edges per block in hist/bucket passes

// ---------------------------------------------------------------------------
// Zero ints (grid-stride)
// ---------------------------------------------------------------------------
__global__ void zero_i_kernel(int* __restrict__ p, int n) {
    int i = blockIdx.x * blockDim.x + threadIdx.x;
    int s = gridDim.x * blockDim.x;
    for (; i < n; i += s) p[i] = 0;
}

// ---------------------------------------------------------------------------
// Bucket-level histogram (LDS-aggregated; no per-node atomics)
// ---------------------------------------------------------------------------
__global__ __launch_bounds__(256) void hist_kernel(
        const int* __restrict__ col, int* __restrict__ bhist, int E, int nbuck) {
    __shared__ int h[NBUCK_MAX];
    for (int i = threadIdx.x; i < nbuck; i += 256) h[i] = 0;
    __syncthreads();

    const int base = blockIdx.x * EPB;
    const int end  = min(base + EPB, E);
    for (int e = base + threadIdx.x; e < end; e += 256)
        atomicAdd(&h[col[e] >> BSHIFT], 1);
    __syncthreads();

    for (int i = threadIdx.x; i < nbuck; i += 256) {
        int v = h[i];
        if (v) atomicAdd(&bhist[i], v);
    }
}

// ---------------------------------------------------------------------------
// Exclusive scan of bhist -> bstart[0..nbuck]  (single block, 8 elems/thread)
// ---------------------------------------------------------------------------
__global__ __launch_bounds__(256) void scanb_kernel(
        const int* __restrict__ bhist, int* __restrict__ bstart, int nbuck) {
    __shared__ int ssum[256];
    const int t = threadIdx.x;
    int v[8];
    int run = 0;
#pragma unroll
    for (int j = 0; j < 8; ++j) {
        int idx = t * 8 + j;
        int x = (idx < nbuck) ? bhist[idx] : 0;
        v[j] = run;
        run += x;
    }
    ssum[t] = run;
    __syncthreads();
    for (int off = 1; off < 256; off <<= 1) {
        int tmp = (t >= off) ? ssum[t - off] : 0;
        __syncthreads();
        ssum[t] += tmp;
        __syncthreads();
    }
    int offset = (t > 0) ? ssum[t - 1] : 0;
#pragma unroll
    for (int j = 0; j < 8; ++j) {
        int idx = t * 8 + j;
        if (idx < nbuck) bstart[idx] = offset + v[j];
    }
    if (t == 255) bstart[nbuck] = ssum[255];   // total = E
}

// ---------------------------------------------------------------------------
// Scatter edges into bucket-major tmp, packed (r<<6 | c&63).
// Block-aggregated reserve -> per-bucket ~sequential write runs.
// ---------------------------------------------------------------------------
__global__ __launch_bounds__(256) void bucket_kernel(
        const int* __restrict__ eidx, const int* __restrict__ bstart,
        int* __restrict__ bcursor, int* __restrict__ tmp, int E, int nbuck) {
    __shared__ int hcnt[NBUCK_MAX];
    __shared__ int hbase[NBUCK_MAX];
    for (int i = threadIdx.x; i < nbuck; i += 256) hcnt[i] = 0;
    __syncthreads();

    const int base = blockIdx.x * EPB;
    const int end  = min(base + EPB, E);

    for (int e = base + threadIdx.x; e < end; e += 256)
        atomicAdd(&hcnt[eidx[E + e] >> BSHIFT], 1);
    __syncthreads();

    for (int i = threadIdx.x; i < nbuck; i += 256) {
        int n = hcnt[i];
        hbase[i] = n ? (bstart[i] + atomicAdd(&bcursor[i], n)) : 0;
        hcnt[i] = 0;           // reuse as local cursor
    }
    __syncthreads();

    for (int e = base + threadIdx.x; e < end; e += 256) {
        int r = eidx[e];
        int c = eidx[E + e];
        int bb = c >> BSHIFT;
        int ofs = atomicAdd(&hcnt[bb], 1);
        tmp[hbase[bb] + ofs] = (r << BSHIFT) | (c & (BSZ - 1));
    }
}

// ---------------------------------------------------------------------------
// Per-bucket: count 64 node degrees in LDS -> rowptr + dis (byproducts),
// then exact CSR placement. All traffic is the bucket's own ~4KB region.
// ---------------------------------------------------------------------------
__global__ __launch_bounds__(256) void sortloc_kernel(
        const int* __restrict__ tmp, const int* __restrict__ bstart,
        int* __restrict__ src, int* __restrict__ rowptr, float* __restrict__ dis,
        int N) {
    __shared__ int cnt[BSZ];
    __shared__ int pref[BSZ];
    __shared__ int scur[BSZ];

    const int bucket = blockIdx.x;
    const int sbeg = bstart[bucket];
    const int send = bstart[bucket + 1];
    const int tid = threadIdx.x;

    if (tid < BSZ) { cnt[tid] = 0; scur[tid] = 0; }
    __syncthreads();

    // pass 1: per-node counts
    for (int i = sbeg + tid; i < send; i += 256)
        atomicAdd(&cnt[tmp[i] & (BSZ - 1)], 1);
    __syncthreads();

    // tiny serial prefix (64 iterations by thread 0)
    if (tid == 0) {
        int run = 0;
#pragma unroll
        for (int j = 0; j < BSZ; ++j) { pref[j] = run; run += cnt[j]; }
    }
    __syncthreads();

    // emit rowptr + dis
    if (tid < BSZ) {
        int node = (bucket << BSHIFT) + tid;
        if (node < N) {
            rowptr[node] = sbeg + pref[tid];
            float d = (float)cnt[tid];
            dis[node] = (d > 0.f) ? rsqrtf(d) : 0.f;
        }
    }
    __syncthreads();

    // pass 2: exact placement (region is L2-hot)
    for (int i = sbeg + tid; i < send; i += 256) {
        int p = tmp[i];
        int c = p & (BSZ - 1);
        int pos = sbeg + pref[c] + atomicAdd(&scur[c], 1);
        src[pos] = p >> BSHIFT;
    }
}

// ---------------------------------------------------------------------------
// hs = (x @ W) * dis[row]
// ---------------------------------------------------------------------------
__global__ __launch_bounds__(256) void linear_kernel(
        const float* __restrict__ x, const float* __restrict__ W,
        const float* __restrict__ dis, float* __restrict__ hs, int nrows) {
    __shared__ float sW[IN_DIM * OUT_DIM];   // 32 KB
    __shared__ float sx[4][IN_DIM];

    const int tid = threadIdx.x;
    for (int i = tid; i < IN_DIM * OUT_DIM; i += 256) sW[i] = W[i];
    __syncthreads();

    const int wave = tid >> 6;
    const int lane = tid & 63;

    for (int r = blockIdx.x * 4 + wave; r < nrows; r += gridDim.x * 4) {
        sx[wave][lane]      = x[(size_t)r * IN_DIM + lane];
        sx[wave][lane + 64] = x[(size_t)r * IN_DIM + 64 + lane];

        float acc = 0.f;
#pragma unroll
        for (int k = 0; k < IN_DIM; k += 4) {
            float4 xv = *reinterpret_cast<const float4*>(&sx[wave][k]);
            acc = fmaf(xv.x, sW[(k + 0) * OUT_DIM + lane], acc);
            acc = fmaf(xv.y, sW[(k + 1) * OUT_DIM + lane], acc);
            acc = fmaf(xv.z, sW[(k + 2) * OUT_DIM + lane], acc);
            acc = fmaf(xv.w, sW[(k + 3) * OUT_DIM + lane], acc);
        }
        hs[(size_t)r * OUT_DIM + lane] = acc * dis[r];
    }
}

// ---------------------------------------------------------------------------
// Aggregate + bias + PReLU: one wave per target node, lane = column
// ---------------------------------------------------------------------------
__global__ __launch_bounds__(256) void agg_kernel(
        const int* __restrict__ rowptr, const int* __restrict__ src,
        const float* __restrict__ hs, const float* __restrict__ dis,
        const float* __restrict__ b, const float* __restrict__ prelu_a,
        float* __restrict__ out, int N, int E) {
    const int lane = threadIdx.x & 63;
    const int node = (blockIdx.x * blockDim.x + threadIdx.x) >> 6;
    if (node >= N) return;

    const int beg = rowptr[node];
    const int end = (node + 1 < N) ? rowptr[node + 1] : E;

    float acc = 0.f;
    int p = beg;
    for (; p + 4 <= end; p += 4) {
        int r0 = src[p], r1 = src[p + 1], r2 = src[p + 2], r3 = src[p + 3];
        float v0 = hs[(size_t)r0 * OUT_DIM + lane];
        float v1 = hs[(size_t)r1 * OUT_DIM + lane];
        float v2 = hs[(size_t)r2 * OUT_DIM + lane];
        float v3 = hs[(size_t)r3 * OUT_DIM + lane];
        acc += v0 + v1 + v2 + v3;
    }
    for (; p < end; ++p) acc += hs[(size_t)src[p] * OUT_DIM + lane];

    float o = acc * dis[node] + b[lane];
    out[(size_t)node * OUT_DIM + lane] = (o >= 0.f) ? o : prelu_a[0] * o;
}

extern "C" void kernel_launch(void* const* d_in, const int* in_sizes, int n_in,
                              void* d_out, int out_size, void* d_ws, size_t ws_size,
                              hipStream_t stream) {
    const float* x    = (const float*)d_in[0];
    const int*   eidx = (const int*)d_in[1];
    const float* W    = (const float*)d_in[2];
    const float* b    = (const float*)d_in[3];
    const float* pa   = (const float*)d_in[4];
    float* out = (float*)d_out;

    const int N = in_sizes[0] / IN_DIM;        // 100000
    const int E = in_sizes[1] / 2;             // 1600000
    const int nbuck = (N + BSZ - 1) >> BSHIFT; // 1563
    const int nchunk = (E + EPB - 1) / EPB;    // 391

    // workspace layout (4-byte elements):
    float* hs      = (float*)d_ws;                       // N*64
    int*   bhist   = (int*)(hs + (size_t)N * OUT_DIM);   // NBUCK_MAX
    int*   bcursor = bhist + NBUCK_MAX;                  // NBUCK_MAX
    int*   bstart  = bcursor + NBUCK_MAX;                // NBUCK_MAX+1
    int*   rowptr  = bstart + NBUCK_MAX + 1;             // N
    float* dis     = (float*)(rowptr + N);               // N
    int*   tmp     = (int*)(dis + N);                    // E
    int*   src     = tmp + E;                            // E

    // 1) zero bhist + bcursor (contiguous, tiny)
    zero_i_kernel<<<16, 256, 0, stream>>>(bhist, 2 * NBUCK_MAX);

    // 2) bucket histogram
    hist_kernel<<<nchunk, 256, 0, stream>>>(eidx + E, bhist, E, nbuck);

    // 3) scan bhist -> bstart (+ total)
    scanb_kernel<<<1, 256, 0, stream>>>(bhist, bstart, nbuck);

    // 4) bucket-major scatter
    bucket_kernel<<<nchunk, 256, 0, stream>>>(eidx, bstart, bcursor, tmp, E, nbuck);

    // 5) per-bucket placement; emits rowptr + dis
    sortloc_kernel<<<nbuck, 256, 0, stream>>>(tmp, bstart, src, rowptr, dis, N);

    // 6) hs = (x @ W) * dis[row]
    linear_kernel<<<2048, 256, 0, stream>>>(x, W, dis, hs, N);

    // 7) aggregate + bias + PReLU
    agg_kernel<<<(N * 64 + 255) / 256, 256, 0, stream>>>(
        rowptr, src, hs, dis, b, pa, out, N, E);
}

// Round 6
// 170.048 us; speedup vs baseline: 4.4908x; 1.0933x over previous
//
#include <hip/hip_runtime.h>

#define IN_DIM     128
#define OUT_DIM    64
#define BSHIFT     6                  // 64 nodes per bucket
#define BSZ        64
#define NBUCK_MAX  2048               // covers N <= 131072
#define EPB        4096               // edges per block in hist/bucket passes

// bf16 helpers (manual RNE pack, bit-shift unpack)
__device__ __forceinline__ unsigned int f2bf_rne(float f) {
    unsigned int b = __float_as_uint(f);
    return (b + 0x7FFFu + ((b >> 16) & 1u)) >> 16;
}
__device__ __forceinline__ float bf_lo(unsigned int v) { return __uint_as_float(v << 16); }
__device__ __forceinline__ float bf_hi(unsigned int v) { return __uint_as_float(v & 0xFFFF0000u); }

// ---------------------------------------------------------------------------
// Zero ints (grid-stride)
// ---------------------------------------------------------------------------
__global__ void zero_i_kernel(int* __restrict__ p, int n) {
    int i = blockIdx.x * blockDim.x + threadIdx.x;
    int s = gridDim.x * blockDim.x;
    for (; i < n; i += s) p[i] = 0;
}

// ---------------------------------------------------------------------------
// Bucket-level histogram (LDS-aggregated; no per-node atomics)
// ---------------------------------------------------------------------------
__global__ __launch_bounds__(256) void hist_kernel(
        const int* __restrict__ col, int* __restrict__ bhist, int E, int nbuck) {
    __shared__ int h[NBUCK_MAX];
    for (int i = threadIdx.x; i < nbuck; i += 256) h[i] = 0;
    __syncthreads();

    const int base = blockIdx.x * EPB;
    const int end  = min(base + EPB, E);
    for (int e = base + threadIdx.x; e < end; e += 256)
        atomicAdd(&h[col[e] >> BSHIFT], 1);
    __syncthreads();

    for (int i = threadIdx.x; i < nbuck; i += 256) {
        int v = h[i];
        if (v) atomicAdd(&bhist[i], v);
    }
}

// ---------------------------------------------------------------------------
// Exclusive scan of bhist -> bstart[0..nbuck]  (single block, 8 elems/thread)
// ---------------------------------------------------------------------------
__global__ __launch_bounds__(256) void scanb_kernel(
        const int* __restrict__ bhist, int* __restrict__ bstart, int nbuck) {
    __shared__ int ssum[256];
    const int t = threadIdx.x;
    int v[8];
    int run = 0;
#pragma unroll
    for (int j = 0; j < 8; ++j) {
        int idx = t * 8 + j;
        int x = (idx < nbuck) ? bhist[idx] : 0;
        v[j] = run;
        run += x;
    }
    ssum[t] = run;
    __syncthreads();
    for (int off = 1; off < 256; off <<= 1) {
        int tmp = (t >= off) ? ssum[t - off] : 0;
        __syncthreads();
        ssum[t] += tmp;
        __syncthreads();
    }
    int offset = (t > 0) ? ssum[t - 1] : 0;
#pragma unroll
    for (int j = 0; j < 8; ++j) {
        int idx = t * 8 + j;
        if (idx < nbuck) bstart[idx] = offset + v[j];
    }
    if (t == 255) bstart[nbuck] = ssum[255];   // total = E
}

// ---------------------------------------------------------------------------
// Scatter edges into bucket-major tmp, packed (r<<6 | c&63).
// Block-aggregated reserve -> per-bucket ~sequential write runs.
// ---------------------------------------------------------------------------
__global__ __launch_bounds__(256) void bucket_kernel(
        const int* __restrict__ eidx, const int* __restrict__ bstart,
        int* __restrict__ bcursor, int* __restrict__ tmp, int E, int nbuck) {
    __shared__ int hcnt[NBUCK_MAX];
    __shared__ int hbase[NBUCK_MAX];
    for (int i = threadIdx.x; i < nbuck; i += 256) hcnt[i] = 0;
    __syncthreads();

    const int base = blockIdx.x * EPB;
    const int end  = min(base + EPB, E);

    for (int e = base + threadIdx.x; e < end; e += 256)
        atomicAdd(&hcnt[eidx[E + e] >> BSHIFT], 1);
    __syncthreads();

    for (int i = threadIdx.x; i < nbuck; i += 256) {
        int n = hcnt[i];
        hbase[i] = n ? (bstart[i] + atomicAdd(&bcursor[i], n)) : 0;
        hcnt[i] = 0;           // reuse as local cursor
    }
    __syncthreads();

    for (int e = base + threadIdx.x; e < end; e += 256) {
        int r = eidx[e];
        int c = eidx[E + e];
        int bb = c >> BSHIFT;
        int ofs = atomicAdd(&hcnt[bb], 1);
        tmp[hbase[bb] + ofs] = (r << BSHIFT) | (c & (BSZ - 1));
    }
}

// ---------------------------------------------------------------------------
// Per-bucket: count 64 node degrees in LDS -> rowptr + dis (byproducts),
// then exact CSR placement. All traffic is the bucket's own ~4KB region.
// ---------------------------------------------------------------------------
__global__ __launch_bounds__(256) void sortloc_kernel(
        const int* __restrict__ tmp, const int* __restrict__ bstart,
        int* __restrict__ src, int* __restrict__ rowptr, float* __restrict__ dis,
        int N) {
    __shared__ int cnt[BSZ];
    __shared__ int pref[BSZ];
    __shared__ int scur[BSZ];

    const int bucket = blockIdx.x;
    const int sbeg = bstart[bucket];
    const int send = bstart[bucket + 1];
    const int tid = threadIdx.x;

    if (tid < BSZ) { cnt[tid] = 0; scur[tid] = 0; }
    __syncthreads();

    for (int i = sbeg + tid; i < send; i += 256)
        atomicAdd(&cnt[tmp[i] & (BSZ - 1)], 1);
    __syncthreads();

    if (tid == 0) {
        int run = 0;
#pragma unroll
        for (int j = 0; j < BSZ; ++j) { pref[j] = run; run += cnt[j]; }
    }
    __syncthreads();

    if (tid < BSZ) {
        int node = (bucket << BSHIFT) + tid;
        if (node < N) {
            rowptr[node] = sbeg + pref[tid];
            float d = (float)cnt[tid];
            dis[node] = (d > 0.f) ? rsqrtf(d) : 0.f;
        }
    }
    __syncthreads();

    for (int i = sbeg + tid; i < send; i += 256) {
        int p = tmp[i];
        int c = p & (BSZ - 1);
        int pos = sbeg + pref[c] + atomicAdd(&scur[c], 1);
        src[pos] = p >> BSHIFT;
    }
}

// ---------------------------------------------------------------------------
// hsb = bf16( (x @ W) * dis[row] )  packed 2 cols/uint: N rows x 32 uints
// ---------------------------------------------------------------------------
__global__ __launch_bounds__(256) void linear_kernel(
        const float* __restrict__ x, const float* __restrict__ W,
        const float* __restrict__ dis, unsigned int* __restrict__ hsb, int nrows) {
    __shared__ float sW[IN_DIM * OUT_DIM];   // 32 KB
    __shared__ float sx[4][IN_DIM];

    const int tid = threadIdx.x;
    for (int i = tid; i < IN_DIM * OUT_DIM; i += 256) sW[i] = W[i];
    __syncthreads();

    const int wave = tid >> 6;
    const int lane = tid & 63;

    for (int r = blockIdx.x * 4 + wave; r < nrows; r += gridDim.x * 4) {
        sx[wave][lane]      = x[(size_t)r * IN_DIM + lane];
        sx[wave][lane + 64] = x[(size_t)r * IN_DIM + 64 + lane];

        float acc = 0.f;
#pragma unroll
        for (int k = 0; k < IN_DIM; k += 4) {
            float4 xv = *reinterpret_cast<const float4*>(&sx[wave][k]);
            acc = fmaf(xv.x, sW[(k + 0) * OUT_DIM + lane], acc);
            acc = fmaf(xv.y, sW[(k + 1) * OUT_DIM + lane], acc);
            acc = fmaf(xv.z, sW[(k + 2) * OUT_DIM + lane], acc);
            acc = fmaf(xv.w, sW[(k + 3) * OUT_DIM + lane], acc);
        }
        float accf = acc * dis[r];
        float nxt = __shfl_down(accf, 1, 64);
        if ((lane & 1) == 0) {
            unsigned int pk = f2bf_rne(accf) | (f2bf_rne(nxt) << 16);
            hsb[(size_t)r * (OUT_DIM / 2) + (lane >> 1)] = pk;
        }
    }
}

// ---------------------------------------------------------------------------
// Aggregate + bias + PReLU: one wave per target node; each 32-lane half
// processes its own edge (32 lanes x bf16x2 = 128B row), halves combined
// at the end via shfl_xor(32).
// ---------------------------------------------------------------------------
__global__ __launch_bounds__(256) void agg_kernel(
        const int* __restrict__ rowptr, const int* __restrict__ src,
        const unsigned int* __restrict__ hsb, const float* __restrict__ dis,
        const float* __restrict__ b, const float* __restrict__ prelu_a,
        float* __restrict__ out, int N, int E) {
    const int lane = threadIdx.x & 63;
    const int half = lane >> 5;
    const int l32  = lane & 31;
    const int node = (blockIdx.x * blockDim.x + threadIdx.x) >> 6;
    if (node >= N) return;

    const int beg = rowptr[node];
    const int end = (node + 1 < N) ? rowptr[node + 1] : E;

    float a0 = 0.f, a1 = 0.f;
    int p = beg + half;
    // 4 independent gathers in flight per half-wave
    for (; p + 6 < end; p += 8) {
        int r0 = src[p], r1 = src[p + 2], r2 = src[p + 4], r3 = src[p + 6];
        unsigned int v0 = hsb[(size_t)r0 * (OUT_DIM / 2) + l32];
        unsigned int v1 = hsb[(size_t)r1 * (OUT_DIM / 2) + l32];
        unsigned int v2 = hsb[(size_t)r2 * (OUT_DIM / 2) + l32];
        unsigned int v3 = hsb[(size_t)r3 * (OUT_DIM / 2) + l32];
        a0 += bf_lo(v0) + bf_lo(v1) + bf_lo(v2) + bf_lo(v3);
        a1 += bf_hi(v0) + bf_hi(v1) + bf_hi(v2) + bf_hi(v3);
    }
    for (; p < end; p += 2) {
        unsigned int v = hsb[(size_t)src[p] * (OUT_DIM / 2) + l32];
        a0 += bf_lo(v);
        a1 += bf_hi(v);
    }

    // combine the two halves
    a0 += __shfl_xor(a0, 32, 64);
    a1 += __shfl_xor(a1, 32, 64);

    if (half == 0) {
        const float dn = dis[node];
        const float pa = prelu_a[0];
        int c0 = l32 * 2;
        float o0 = a0 * dn + b[c0];
        float o1 = a1 * dn + b[c0 + 1];
        o0 = (o0 >= 0.f) ? o0 : pa * o0;
        o1 = (o1 >= 0.f) ? o1 : pa * o1;
        *reinterpret_cast<float2*>(&out[(size_t)node * OUT_DIM + c0]) = make_float2(o0, o1);
    }
}

extern "C" void kernel_launch(void* const* d_in, const int* in_sizes, int n_in,
                              void* d_out, int out_size, void* d_ws, size_t ws_size,
                              hipStream_t stream) {
    const float* x    = (const float*)d_in[0];
    const int*   eidx = (const int*)d_in[1];
    const float* W    = (const float*)d_in[2];
    const float* b    = (const float*)d_in[3];
    const float* pa   = (const float*)d_in[4];
    float* out = (float*)d_out;

    const int N = in_sizes[0] / IN_DIM;        // 100000
    const int E = in_sizes[1] / 2;             // 1600000
    const int nbuck = (N + BSZ - 1) >> BSHIFT; // 1563
    const int nchunk = (E + EPB - 1) / EPB;    // 391

    // workspace layout (4-byte elements):
    unsigned int* hsb = (unsigned int*)d_ws;             // N*32 (bf16x2)
    int*   bhist   = (int*)(hsb + (size_t)N * (OUT_DIM / 2)); // NBUCK_MAX
    int*   bcursor = bhist + NBUCK_MAX;                  // NBUCK_MAX
    int*   bstart  = bcursor + NBUCK_MAX;                // NBUCK_MAX+1
    int*   rowptr  = bstart + NBUCK_MAX + 1;             // N
    float* dis     = (float*)(rowptr + N);               // N
    int*   tmp     = (int*)(dis + N);                    // E
    int*   src     = tmp + E;                            // E

    // 1) zero bhist + bcursor (contiguous, tiny)
    zero_i_kernel<<<16, 256, 0, stream>>>(bhist, 2 * NBUCK_MAX);

    // 2) bucket histogram
    hist_kernel<<<nchunk, 256, 0, stream>>>(eidx + E, bhist, E, nbuck);

    // 3) scan bhist -> bstart (+ total)
    scanb_kernel<<<1, 256, 0, stream>>>(bhist, bstart, nbuck);

    // 4) bucket-major scatter
    bucket_kernel<<<nchunk, 256, 0, stream>>>(eidx, bstart, bcursor, tmp, E, nbuck);

    // 5) per-bucket placement; emits rowptr + dis
    sortloc_kernel<<<nbuck, 256, 0, stream>>>(tmp, bstart, src, rowptr, dis, N);

    // 6) hsb = bf16((x @ W) * dis[row])
    linear_kernel<<<2048, 256, 0, stream>>>(x, W, dis, hsb, N);

    // 7) aggregate + bias + PReLU
    agg_kernel<<<(N * 64 + 255) / 256, 256, 0, stream>>>(
        rowptr, src, hsb, dis, b, pa, out, N, E);
}

// Round 7
// 169.328 us; speedup vs baseline: 4.5099x; 1.0042x over previous
//
#include <hip/hip_runtime.h>

#define IN_DIM     128
#define OUT_DIM    64
#define BSHIFT     6                  // 64 nodes per bucket
#define BSZ        64
#define NBUCK_MAX  2048               // covers N <= 131072
#define EPB        4096               // edges per block in hist/bucket passes

// bf16 helpers (manual RNE pack, bit-shift unpack)
__device__ __forceinline__ unsigned int f2bf_rne(float f) {
    unsigned int b = __float_as_uint(f);
    return (b + 0x7FFFu + ((b >> 16) & 1u)) >> 16;
}
__device__ __forceinline__ float bf_lo(unsigned int v) { return __uint_as_float(v << 16); }
__device__ __forceinline__ float bf_hi(unsigned int v) { return __uint_as_float(v & 0xFFFF0000u); }

// ---------------------------------------------------------------------------
// Zero ints (grid-stride)
// ---------------------------------------------------------------------------
__global__ void zero_i_kernel(int* __restrict__ p, int n) {
    int i = blockIdx.x * blockDim.x + threadIdx.x;
    int s = gridDim.x * blockDim.x;
    for (; i < n; i += s) p[i] = 0;
}

// ---------------------------------------------------------------------------
// Bucket-level histogram (LDS-aggregated; no per-node atomics)
// ---------------------------------------------------------------------------
__global__ __launch_bounds__(256) void hist_kernel(
        const int* __restrict__ col, int* __restrict__ bhist, int E, int nbuck) {
    __shared__ int h[NBUCK_MAX];
    for (int i = threadIdx.x; i < nbuck; i += 256) h[i] = 0;
    __syncthreads();

    const int base = blockIdx.x * EPB;
    const int end  = min(base + EPB, E);
    for (int e = base + threadIdx.x; e < end; e += 256)
        atomicAdd(&h[col[e] >> BSHIFT], 1);
    __syncthreads();

    for (int i = threadIdx.x; i < nbuck; i += 256) {
        int v = h[i];
        if (v) atomicAdd(&bhist[i], v);
    }
}

// ---------------------------------------------------------------------------
// Exclusive scan of bhist -> bstart[0..nbuck]  (single block, 8 elems/thread)
// ---------------------------------------------------------------------------
__global__ __launch_bounds__(256) void scanb_kernel(
        const int* __restrict__ bhist, int* __restrict__ bstart, int nbuck) {
    __shared__ int ssum[256];
    const int t = threadIdx.x;
    int v[8];
    int run = 0;
#pragma unroll
    for (int j = 0; j < 8; ++j) {
        int idx = t * 8 + j;
        int x = (idx < nbuck) ? bhist[idx] : 0;
        v[j] = run;
        run += x;
    }
    ssum[t] = run;
    __syncthreads();
    for (int off = 1; off < 256; off <<= 1) {
        int tmp = (t >= off) ? ssum[t - off] : 0;
        __syncthreads();
        ssum[t] += tmp;
        __syncthreads();
    }
    int offset = (t > 0) ? ssum[t - 1] : 0;
#pragma unroll
    for (int j = 0; j < 8; ++j) {
        int idx = t * 8 + j;
        if (idx < nbuck) bstart[idx] = offset + v[j];
    }
    if (t == 255) bstart[nbuck] = ssum[255];   // total = E
}

// ---------------------------------------------------------------------------
// Scatter edges into bucket-major tmp, packed (r<<6 | c&63).
// Block-aggregated reserve -> per-bucket ~sequential write runs.
// ---------------------------------------------------------------------------
__global__ __launch_bounds__(256) void bucket_kernel(
        const int* __restrict__ eidx, const int* __restrict__ bstart,
        int* __restrict__ bcursor, int* __restrict__ tmp, int E, int nbuck) {
    __shared__ int hcnt[NBUCK_MAX];
    __shared__ int hbase[NBUCK_MAX];
    for (int i = threadIdx.x; i < nbuck; i += 256) hcnt[i] = 0;
    __syncthreads();

    const int base = blockIdx.x * EPB;
    const int end  = min(base + EPB, E);

    for (int e = base + threadIdx.x; e < end; e += 256)
        atomicAdd(&hcnt[eidx[E + e] >> BSHIFT], 1);
    __syncthreads();

    for (int i = threadIdx.x; i < nbuck; i += 256) {
        int n = hcnt[i];
        hbase[i] = n ? (bstart[i] + atomicAdd(&bcursor[i], n)) : 0;
        hcnt[i] = 0;           // reuse as local cursor
    }
    __syncthreads();

    for (int e = base + threadIdx.x; e < end; e += 256) {
        int r = eidx[e];
        int c = eidx[E + e];
        int bb = c >> BSHIFT;
        int ofs = atomicAdd(&hcnt[bb], 1);
        tmp[hbase[bb] + ofs] = (r << BSHIFT) | (c & (BSZ - 1));
    }
}

// ---------------------------------------------------------------------------
// Per-bucket: count 64 node degrees in LDS -> rowptr + dis (byproducts),
// then exact CSR placement. All traffic is the bucket's own ~4KB region.
// ---------------------------------------------------------------------------
__global__ __launch_bounds__(256) void sortloc_kernel(
        const int* __restrict__ tmp, const int* __restrict__ bstart,
        int* __restrict__ src, int* __restrict__ rowptr, float* __restrict__ dis,
        int N) {
    __shared__ int cnt[BSZ];
    __shared__ int pref[BSZ];
    __shared__ int scur[BSZ];

    const int bucket = blockIdx.x;
    const int sbeg = bstart[bucket];
    const int send = bstart[bucket + 1];
    const int tid = threadIdx.x;

    if (tid < BSZ) { cnt[tid] = 0; scur[tid] = 0; }
    __syncthreads();

    for (int i = sbeg + tid; i < send; i += 256)
        atomicAdd(&cnt[tmp[i] & (BSZ - 1)], 1);
    __syncthreads();

    if (tid == 0) {
        int run = 0;
#pragma unroll
        for (int j = 0; j < BSZ; ++j) { pref[j] = run; run += cnt[j]; }
    }
    __syncthreads();

    if (tid < BSZ) {
        int node = (bucket << BSHIFT) + tid;
        if (node < N) {
            rowptr[node] = sbeg + pref[tid];
            float d = (float)cnt[tid];
            dis[node] = (d > 0.f) ? rsqrtf(d) : 0.f;
        }
    }
    __syncthreads();

    for (int i = sbeg + tid; i < send; i += 256) {
        int p = tmp[i];
        int c = p & (BSZ - 1);
        int pos = sbeg + pref[c] + atomicAdd(&scur[c], 1);
        src[pos] = p >> BSHIFT;
    }
}

// ---------------------------------------------------------------------------
// hsb = bf16( (x @ W) * dis[row] )  packed 2 cols/uint: N rows x 32 uints
// ---------------------------------------------------------------------------
__global__ __launch_bounds__(256) void linear_kernel(
        const float* __restrict__ x, const float* __restrict__ W,
        const float* __restrict__ dis, unsigned int* __restrict__ hsb, int nrows) {
    __shared__ float sW[IN_DIM * OUT_DIM];   // 32 KB
    __shared__ float sx[4][IN_DIM];

    const int tid = threadIdx.x;
    for (int i = tid; i < IN_DIM * OUT_DIM; i += 256) sW[i] = W[i];
    __syncthreads();

    const int wave = tid >> 6;
    const int lane = tid & 63;

    for (int r = blockIdx.x * 4 + wave; r < nrows; r += gridDim.x * 4) {
        sx[wave][lane]      = x[(size_t)r * IN_DIM + lane];
        sx[wave][lane + 64] = x[(size_t)r * IN_DIM + 64 + lane];

        float acc = 0.f;
#pragma unroll
        for (int k = 0; k < IN_DIM; k += 4) {
            float4 xv = *reinterpret_cast<const float4*>(&sx[wave][k]);
            acc = fmaf(xv.x, sW[(k + 0) * OUT_DIM + lane], acc);
            acc = fmaf(xv.y, sW[(k + 1) * OUT_DIM + lane], acc);
            acc = fmaf(xv.z, sW[(k + 2) * OUT_DIM + lane], acc);
            acc = fmaf(xv.w, sW[(k + 3) * OUT_DIM + lane], acc);
        }
        float accf = acc * dis[r];
        float nxt = __shfl_down(accf, 1, 64);
        if ((lane & 1) == 0) {
            unsigned int pk = f2bf_rne(accf) | (f2bf_rne(nxt) << 16);
            hsb[(size_t)r * (OUT_DIM / 2) + (lane >> 1)] = pk;
        }
    }
}

// ---------------------------------------------------------------------------
// Aggregate + bias + PReLU: one wave per target node; each 32-lane half
// processes its own edge (32 lanes x bf16x2 = 128B row), halves combined
// at the end via shfl_xor(32).
// ---------------------------------------------------------------------------
__global__ __launch_bounds__(256) void agg_kernel(
        const int* __restrict__ rowptr, const int* __restrict__ src,
        const unsigned int* __restrict__ hsb, const float* __restrict__ dis,
        const float* __restrict__ b, const float* __restrict__ prelu_a,
        float* __restrict__ out, int N, int E) {
    const int lane = threadIdx.x & 63;
    const int half = lane >> 5;
    const int l32  = lane & 31;
    const int node = (blockIdx.x * blockDim.x + threadIdx.x) >> 6;
    if (node >= N) return;

    const int beg = rowptr[node];
    const int end = (node + 1 < N) ? rowptr[node + 1] : E;

    float a0 = 0.f, a1 = 0.f;
    int p = beg + half;
    // 4 independent gathers in flight per half-wave
    for (; p + 6 < end; p += 8) {
        int r0 = src[p], r1 = src[p + 2], r2 = src[p + 4], r3 = src[p + 6];
        unsigned int v0 = hsb[(size_t)r0 * (OUT_DIM / 2) + l32];
        unsigned int v1 = hsb[(size_t)r1 * (OUT_DIM / 2) + l32];
        unsigned int v2 = hsb[(size_t)r2 * (OUT_DIM / 2) + l32];
        unsigned int v3 = hsb[(size_t)r3 * (OUT_DIM / 2) + l32];
        a0 += bf_lo(v0) + bf_lo(v1) + bf_lo(v2) + bf_lo(v3);
        a1 += bf_hi(v0) + bf_hi(v1) + bf_hi(v2) + bf_hi(v3);
    }
    for (; p < end; p += 2) {
        unsigned int v = hsb[(size_t)src[p] * (OUT_DIM / 2) + l32];
        a0 += bf_lo(v);
        a1 += bf_hi(v);
    }

    // combine the two halves
    a0 += __shfl_xor(a0, 32, 64);
    a1 += __shfl_xor(a1, 32, 64);

    if (half == 0) {
        const float dn = dis[node];
        const float pa = prelu_a[0];
        int c0 = l32 * 2;
        float o0 = a0 * dn + b[c0];
        float o1 = a1 * dn + b[c0 + 1];
        o0 = (o0 >= 0.f) ? o0 : pa * o0;
        o1 = (o1 >= 0.f) ? o1 : pa * o1;
        *reinterpret_cast<float2*>(&out[(size_t)node * OUT_DIM + c0]) = make_float2(o0, o1);
    }
}

extern "C" void kernel_launch(void* const* d_in, const int* in_sizes, int n_in,
                              void* d_out, int out_size, void* d_ws, size_t ws_size,
                              hipStream_t stream) {
    const float* x    = (const float*)d_in[0];
    const int*   eidx = (const int*)d_in[1];
    const float* W    = (const float*)d_in[2];
    const float* b    = (const float*)d_in[3];
    const float* pa   = (const float*)d_in[4];
    float* out = (float*)d_out;

    const int N = in_sizes[0] / IN_DIM;        // 100000
    const int E = in_sizes[1] / 2;             // 1600000
    const int nbuck = (N + BSZ - 1) >> BSHIFT; // 1563
    const int nchunk = (E + EPB - 1) / EPB;    // 391

    // workspace layout (4-byte elements):
    unsigned int* hsb = (unsigned int*)d_ws;             // N*32 (bf16x2)
    int*   bhist   = (int*)(hsb + (size_t)N * (OUT_DIM / 2)); // NBUCK_MAX
    int*   bcursor = bhist + NBUCK_MAX;                  // NBUCK_MAX
    int*   bstart  = bcursor + NBUCK_MAX;                // NBUCK_MAX+1
    int*   rowptr  = bstart + NBUCK_MAX + 1;             // N
    float* dis     = (float*)(rowptr + N);               // N
    int*   tmp     = (int*)(dis + N);                    // E
    int*   src     = tmp + E;                            // E

    // 1) zero bhist + bcursor (contiguous, tiny)
    zero_i_kernel<<<16, 256, 0, stream>>>(bhist, 2 * NBUCK_MAX);

    // 2) bucket histogram
    hist_kernel<<<nchunk, 256, 0, stream>>>(eidx + E, bhist, E, nbuck);

    // 3) scan bhist -> bstart (+ total)
    scanb_kernel<<<1, 256, 0, stream>>>(bhist, bstart, nbuck);

    // 4) bucket-major scatter
    bucket_kernel<<<nchunk, 256, 0, stream>>>(eidx, bstart, bcursor, tmp, E, nbuck);

    // 5) per-bucket placement; emits rowptr + dis
    sortloc_kernel<<<nbuck, 256, 0, stream>>>(tmp, bstart, src, rowptr, dis, N);

    // 6) hsb = bf16((x @ W) * dis[row])
    linear_kernel<<<2048, 256, 0, stream>>>(x, W, dis, hsb, N);

    // 7) aggregate + bias + PReLU
    agg_kernel<<<(N * 64 + 255) / 256, 256, 0, stream>>>(
        rowptr, src, hsb, dis, b, pa, out, N, E);
}